// Round 2
// baseline (397.462 us; speedup 1.0000x reference)
//
#include <hip/hip_runtime.h>
#include <hip/hip_cooperative_groups.h>

namespace cg = cooperative_groups;

// Problem constants (fixed by reference)
constexpr int N_  = 10000;   // nodes (< 65536 -> u16 src)
constexpr int E_  = 320000;  // edges
constexpr int F1  = 33;      // input features
constexpr int H   = 32;      // hidden
constexpr int G   = 64;      // graphs
constexpr int CAP = 96;      // padded CSR slots/node (deg~Poisson(32), P(overflow)~1e-18/node)
constexpr int NB_ = 1280;    // node-blocks of 8 (covers 10240 >= N_)
constexpr int ROW = CAP * 8; // 768 dwords per node-block row in transposed meta

// Fused cooperative kernel geometry: 256 blocks x 1024 threads = 1 block/CU.
// Cooperative validation needs only 1 block/CU co-residency, which holds under
// every occupancy model: 1024 thr <= 2048, LDS 40.6KB <= 64KB, VGPR <= 128
// via __launch_bounds__(1024,4). Since 256 % 32 == 0, block b's two agg tasks
// (b, b+256) share slice b&31 -> one LDS table fill serves both chunks.
constexpr int GRID   = 256;
constexpr int BT     = 1024;
constexpr int SLICES = 32;
constexpr int CHUNKS = 16;         // 32 slices x 16 chunks = 512 agg tasks (2/block)
constexpr int TILE   = 640;        // 16*640 = 10240 >= N_
constexpr int ITERS  = TILE / 128; // 16 waves x 8 nodes = 128 nodes/iter
constexpr int NG     = 2 * ITERS;  // flat groups per block per agg phase

// round-to-nearest-even f32 -> bf16 (low 16 bits)
__device__ __forceinline__ unsigned bf16r(float x) {
    unsigned u = __float_as_uint(x);
    return (u + 0x7FFFu + ((u >> 16) & 1u)) >> 16;
}

// transposed meta slot address: node n, slot pos
__device__ __forceinline__ size_t mslot(int n, int pos) {
    return (size_t)(n >> 3) * ROW + (size_t)(pos >> 3) * 64 + (n & 7) * 8 + (pos & 7);
}

struct Prm {
    const float* x; const int* ei; const float* ea; const int* batch;
    const float* A1; const float* B1; const float* R1; const float* z1;
    const float* A2; const float* B2; const float* R2; const float* z2;
    const float* A3; const float* B3; const float* R3; const float* z3;
    const float* l1w; const float* l1b; const float* l2w; const float* l2b;
    int* counts; int* startsP; unsigned* meta2;
    unsigned* UV; float* Rs; float* Hs;   // single buffers, reused across layers
    float* out;
};

// ---------------- phase: build meta (edges) + layer-1 precompute + graph starts ----------------

__device__ __forceinline__ void build_phase(const Prm& p, unsigned* uvl) {
    const int tid = threadIdx.x;
    const int bid = blockIdx.x;

    // edge part: grid-stride (2 passes cover 320000)
    for (int e = bid * BT + tid; e < E_; e += GRID * BT) {
        int s = p.ei[e];
        int d = p.ei[E_ + e];
        int pos = atomicAdd(&p.counts[d], 1);
        p.meta2[mslot(d, pos)] = (unsigned)s | (bf16r(p.ea[e]) << 16);
    }

    // node part: tasks of 32 nodes (313 tasks over 256 blocks)
    unsigned (*s_uv)[33] = reinterpret_cast<unsigned (*)[33]>(uvl);
    float    (*s_r )[33] = reinterpret_cast<float (*)[33]>((float*)(uvl + 32 * 33));
    int grp = tid >> 5, f = tid & 31;
    for (int t = bid; t * 32 < N_; t += GRID) {
        int node = t * 32 + grp;
        int nc = min(node, N_ - 1);
        if (f == 0 && node < N_) {   // graph-boundary detection (batch sorted)
            int b = p.batch[nc];
            int bp = (node == 0) ? -1 : p.batch[nc - 1];
            if (b != bp) p.startsP[b] = node + 1;
        }
        float u = 0.f, v = 0.f, r = p.z1[f];
        const float* xr = p.x + (size_t)nc * F1;
        #pragma unroll
        for (int k = 0; k < F1; ++k) {
            float xv = xr[k];
            u = fmaf(xv, p.A1[k * H + f], u);
            v = fmaf(xv, p.B1[k * H + f], v);
            r = fmaf(xv, p.R1[k * H + f], r);
        }
        s_uv[f][grp] = bf16r(u) | (bf16r(v) << 16);
        s_r [f][grp] = r;
        __syncthreads();
        int fo = tid >> 5, nl = tid & 31;
        int on = t * 32 + nl;
        if (on < N_) {
            p.UV[(size_t)fo * N_ + on] = s_uv[fo][nl];
            p.Rs[(size_t)fo * N_ + on] = s_r [fo][nl];
        }
        __syncthreads();
    }
}

// ---------------- phase: per-layer precompute from slice-major h ----------------

__device__ __forceinline__ void pre_phase(const Prm& p, unsigned* uvl,
        const float* __restrict__ A, const float* __restrict__ Bm,
        const float* __restrict__ Rw, const float* __restrict__ bz) {
    const int tid = threadIdx.x;
    unsigned (*s_uv)[33] = reinterpret_cast<unsigned (*)[33]>(uvl);
    float    (*s_r )[33] = reinterpret_cast<float (*)[33]>((float*)(uvl + 32 * 33));
    int grp = tid >> 5, f = tid & 31;
    for (int t = blockIdx.x; t * 32 < N_; t += GRID) {
        int node = t * 32 + grp;
        int nc = min(node, N_ - 1);
        float hv = p.Hs[(size_t)f * N_ + nc];
        float u = 0.f, v = 0.f, r = bz[f];
        #pragma unroll
        for (int k = 0; k < H; ++k) {
            float hk = __shfl(hv, k, 32);
            u = fmaf(hk, A[k * H + f], u);
            v = fmaf(hk, Bm[k * H + f], v);
            r = fmaf(hk, Rw[k * H + f], r);
        }
        s_uv[f][grp] = bf16r(u) | (bf16r(v) << 16);
        s_r [f][grp] = r;
        __syncthreads();
        int fo = tid >> 5, nl = tid & 31;
        int on = t * 32 + nl;
        if (on < N_) {
            p.UV[(size_t)fo * N_ + on] = s_uv[fo][nl];
            p.Rs[(size_t)fo * N_ + on] = s_r [fo][nl];
        }
        __syncthreads();
    }
}

// ---------------- phase: LDS-sliced conv aggregation ----------------
// block b: slice s = b&31, chunks c0 = b>>5 and c0+8 (one LDS fill, 10 groups).
// 16 waves x (8 nodes x 8 slots); always-6 slot groups; rare deep-node tail.

__device__ __forceinline__ void agg_phase(const Prm& p, unsigned* uvl) {
    const int tid = threadIdx.x;
    const int s  = blockIdx.x & 31;
    const int c0 = blockIdx.x >> 5;   // 0..7
    const int l = tid & 63, wav = tid >> 6, j0 = l & 7, nl = l >> 3;

    auto base_of = [&](int g) {
        int ch = c0 + ((g >= ITERS) ? 8 : 0);
        int it = (g >= ITERS) ? (g - ITERS) : g;
        return ch * TILE + it * 128 + wav * 8;
    };

    // ---- initial prefetch for group 0 (overlaps LDS fill) ----
    int cbase = base_of(0);
    int node = cbase + nl;
    int nc = min(node, N_ - 1);
    int dg = (node < N_) ? p.counts[nc] : 0;
    float rv = p.Rs[(size_t)s * N_ + nc];
    const unsigned* mrow = p.meta2 + (size_t)(cbase >> 3) * ROW + l;
    unsigned m0 = mrow[0], m1 = mrow[64], m2 = mrow[128],
             m3 = mrow[192], m4 = mrow[256], m5 = mrow[320];

    // ---- fill LDS with this slice's UV table (coalesced 40 KB, once) ----
    const unsigned* srcp = p.UV + (size_t)s * N_;
    #pragma unroll
    for (int i = 0; i < 3; ++i) {
        int d4 = (i * BT + tid) * 4;
        if (d4 + 4 <= N_)
            *reinterpret_cast<uint4*>(&uvl[d4]) =
                *reinterpret_cast<const uint4*>(srcp + d4);
    }
    __syncthreads();

    for (int g = 0; g < NG; ++g) {
        // ---- prefetch next group ----
        int nbase = 0, nnode = 0, ndg = 0; float nrv = 0.f;
        unsigned n0 = 0, n1 = 0, n2 = 0, n3 = 0, n4 = 0, n5 = 0;
        if (g + 1 < NG) {
            nbase = base_of(g + 1);
            nnode = nbase + nl;
            int nnc = min(nnode, N_ - 1);
            ndg = (nnode < N_) ? p.counts[nnc] : 0;
            nrv = p.Rs[(size_t)s * N_ + nnc];
            const unsigned* nmr = p.meta2 + (size_t)(nbase >> 3) * ROW + l;
            n0 = nmr[0]; n1 = nmr[64]; n2 = nmr[128];
            n3 = nmr[192]; n4 = nmr[256]; n5 = nmr[320];
        }

        // ---- compute current group: always 6 slot groups (48 slots) ----
        float acc = 0.f;
        auto slot = [&](unsigned mv, int pq) {
            unsigned idx = min(mv & 0xFFFFu, (unsigned)(N_ - 1));
            unsigned w = uvl[idx];
            float t = fmaf(__uint_as_float(mv & 0xFFFF0000u),   // a (bf16 hi)
                           __uint_as_float(w << 16),            // u
                           __uint_as_float(w & 0xFFFF0000u));   // v
            if (j0 + 8 * pq < dg) acc += t;
        };
        slot(m0, 0); slot(m1, 1); slot(m2, 2);
        slot(m3, 3); slot(m4, 4); slot(m5, 5);
        if (__any(dg > 48)) {                  // rare deep-node tail (~2% of waves)
            const unsigned* trow = p.meta2 + (size_t)(cbase >> 3) * ROW + l;
            for (int pq = 6; __any(j0 + 8 * pq < dg); ++pq)
                slot(trow[pq * 64], pq);
        }
        acc += __shfl_xor(acc, 1);
        acc += __shfl_xor(acc, 2);
        acc += __shfl_xor(acc, 4);
        float h = fmaxf(rv + acc, 0.f);
        if (j0 == 0 && node < N_) p.Hs[(size_t)s * N_ + node] = h;

        cbase = nbase; node = nnode; dg = ndg; rv = nrv;
        m0 = n0; m1 = n1; m2 = n2; m3 = n3; m4 = n4; m5 = n5;
    }
}

// ---------------- phase: per-graph pooling + readout (blocks 0..63) ----------------

__device__ __forceinline__ void pool_phase(const Prm& p, int* sst, float* gpl) {
    const int tid = threadIdx.x;
    int g = blockIdx.x;
    if (tid < G) sst[tid] = p.startsP[tid];
    __syncthreads();
    int sp = sst[g];
    int s0 = 0, e0 = 0;
    if (sp != 0) {
        s0 = sp - 1;
        e0 = N_;
        for (int j = g + 1; j < G; ++j)
            if (sst[j]) { e0 = sst[j] - 1; break; }
    }
    int f = tid >> 5, oct = tid & 31;
    float sum = 0.f, mx = 0.f;
    for (int n = s0 + oct; n < e0; n += 32) {
        float w = p.Hs[(size_t)f * N_ + n];
        sum += w;
        mx = fmaxf(mx, w);
    }
    #pragma unroll
    for (int o = 1; o <= 16; o <<= 1) {
        sum += __shfl_xor(sum, o);
        mx = fmaxf(mx, __shfl_xor(mx, o));
    }
    if (oct == 0) {
        float c = fmaxf((float)(e0 - s0), 1.0f);
        gpl[f] = sum;
        gpl[H + f] = sum / c;
        gpl[2 * H + f] = mx;
    }
    __syncthreads();
    if (tid < 32) {
        float hacc = p.l1b[tid];
        #pragma unroll
        for (int k = 0; k < H; ++k) {
            hacc = fmaf(gpl[k],         p.l1w[k * H + tid], hacc);
            hacc = fmaf(gpl[H + k],     p.l1w[(H + k) * H + tid], hacc);
            hacc = fmaf(gpl[2 * H + k], p.l1w[(2 * H + k) * H + tid], hacc);
        }
        float hid = fmaxf(hacc, 0.f);
        float p0 = hid * p.l2w[tid * 2 + 0];
        float p1 = hid * p.l2w[tid * 2 + 1];
        #pragma unroll
        for (int o = 16; o; o >>= 1) {
            p0 += __shfl_xor(p0, o, 32);
            p1 += __shfl_xor(p1, o, 32);
        }
        if (tid == 0) {
            float l0 = p0 + p.l2b[0], l1 = p1 + p.l2b[1];
            float m = fmaxf(l0, l1);
            float lse = m + logf(expf(l0 - m) + expf(l1 - m));
            p.out[g * 2 + 0] = l0 - lse;
            p.out[g * 2 + 1] = l1 - lse;
        }
    }
}

// ---------------- fused cooperative kernel: 1 dispatch, 7 grid syncs ----------------

__global__ __launch_bounds__(BT, 4) void k_fused(Prm p) {
    cg::grid_group grid = cg::this_grid();
    __shared__ __align__(16) unsigned uvl[N_];   // 40000 B; aliased for pre staging
    __shared__ int   sst[G];
    __shared__ float gpl[3 * H];
    const int tid = threadIdx.x;
    const int bid = blockIdx.x;

    // P0: zero counts + startsP (replaces the memset dispatch)
    {
        int i = bid * BT + tid;
        if (i < N_) p.counts[i] = 0;
        else if (i < N_ + G) p.startsP[i - N_] = 0;
    }
    grid.sync();

    // P1: build padded CSR + layer-1 UV/R precompute + graph starts
    build_phase(p, uvl);
    grid.sync();

    // P2..P6: conv1 agg -> pre2 -> conv2 agg -> pre3 -> conv3 agg
    agg_phase(p, uvl);
    grid.sync();
    pre_phase(p, uvl, p.A2, p.B2, p.R2, p.z2);
    grid.sync();
    agg_phase(p, uvl);
    grid.sync();
    pre_phase(p, uvl, p.A3, p.B3, p.R3, p.z3);
    grid.sync();
    agg_phase(p, uvl);
    grid.sync();

    // P7: pooling + readout on blocks 0..63 (no further syncs; others exit)
    if (bid < G) pool_phase(p, sst, gpl);
}

// ---------------- fallback wrappers (separate dispatches, same phase code) ----------------

__global__ __launch_bounds__(BT, 4) void kf_build(Prm p) {
    __shared__ __align__(16) unsigned uvl[N_];
    build_phase(p, uvl);
}
__global__ __launch_bounds__(BT, 4) void kf_agg(Prm p) {
    __shared__ __align__(16) unsigned uvl[N_];
    agg_phase(p, uvl);
}
__global__ __launch_bounds__(BT, 4) void kf_pre(Prm p, int layer) {
    __shared__ __align__(16) unsigned uvl[N_];
    if (layer == 2) pre_phase(p, uvl, p.A2, p.B2, p.R2, p.z2);
    else            pre_phase(p, uvl, p.A3, p.B3, p.R3, p.z3);
}
__global__ __launch_bounds__(BT, 4) void kf_pool(Prm p) {
    __shared__ int   sst[G];
    __shared__ float gpl[3 * H];
    pool_phase(p, sst, gpl);
}

// ---------------- launch ----------------

extern "C" void kernel_launch(void* const* d_in, const int* in_sizes, int n_in,
                              void* d_out, int out_size, void* d_ws, size_t ws_size,
                              hipStream_t stream) {
    const float* x      = (const float*)d_in[0];
    const int*   ei     = (const int*)  d_in[1];
    const float* ea     = (const float*)d_in[2];
    const int*   batch  = (const int*)  d_in[3];
    const float* nn_w1  = (const float*)d_in[4];
    const float* nn_b1  = (const float*)d_in[5];
    const float* root1  = (const float*)d_in[6];
    const float* bias1  = (const float*)d_in[7];
    const float* nn_w2  = (const float*)d_in[8];
    const float* nn_b2  = (const float*)d_in[9];
    const float* root2  = (const float*)d_in[10];
    const float* bias2  = (const float*)d_in[11];
    const float* nn_w3  = (const float*)d_in[12];
    const float* nn_b3  = (const float*)d_in[13];
    const float* root3  = (const float*)d_in[14];
    const float* bias3  = (const float*)d_in[15];
    const float* lin1_w = (const float*)d_in[16];
    const float* lin1_b = (const float*)d_in[17];
    const float* lin2_w = (const float*)d_in[18];
    const float* lin2_b = (const float*)d_in[19];
    float* out = (float*)d_out;

    char* ws = (char*)d_ws;
    size_t off = 0;
    auto alloc = [&](size_t bytes) -> void* {
        void* p = ws + off;
        off += (bytes + 255) & ~(size_t)255;
        return p;
    };
    // counts + startsP contiguous (single memset in fallback path)
    const size_t zbytes = N_ * sizeof(int) + G * sizeof(int);
    char* zchunk = (char*)alloc(zbytes);
    int*  counts  = (int*)zchunk;
    int*  startsP = (int*)(zchunk + N_ * sizeof(int));
    unsigned* meta2 = (unsigned*)alloc((size_t)NB_ * ROW * sizeof(unsigned)); // 3.93 MB
    unsigned* UV = (unsigned*)alloc((size_t)H * N_ * sizeof(unsigned));
    float*    Rs = (float*)   alloc((size_t)H * N_ * sizeof(float));
    float*    Hs = (float*)   alloc((size_t)H * N_ * sizeof(float));

    Prm prm{ x, ei, ea, batch,
             nn_w1, nn_b1, root1, bias1,
             nn_w2, nn_b2, root2, bias2,
             nn_w3, nn_b3, root3, bias3,
             lin1_w, lin1_b, lin2_w, lin2_b,
             counts, startsP, meta2, UV, Rs, Hs, out };

    void* args[] = { &prm };
    hipError_t err = hipLaunchCooperativeKernel((const void*)k_fused,
                                                dim3(GRID), dim3(BT),
                                                args, 0, stream);
    if (err != hipSuccess) {
        // Fallback: proven multi-dispatch pipeline using the same phase code.
        hipMemsetAsync(zchunk, 0, zbytes, stream);
        kf_build<<<GRID, BT, 0, stream>>>(prm);
        kf_agg  <<<GRID, BT, 0, stream>>>(prm);
        kf_pre  <<<GRID, BT, 0, stream>>>(prm, 2);
        kf_agg  <<<GRID, BT, 0, stream>>>(prm);
        kf_pre  <<<GRID, BT, 0, stream>>>(prm, 3);
        kf_agg  <<<GRID, BT, 0, stream>>>(prm);
        kf_pool <<<G, BT, 0, stream>>>(prm);
    }
}